// Round 5
// baseline (1802.175 us; speedup 1.0000x reference)
//
#include <hip/hip_runtime.h>
#include <math.h>

#define HID 128

typedef __attribute__((ext_vector_type(8))) short bf16x8;
typedef __attribute__((ext_vector_type(16))) float f32x16;

__device__ __forceinline__ float silu_f(float v) {
    return v / (1.0f + __expf(-v));
}
__device__ __forceinline__ float sigmoid_f(float v) {
    return 1.0f / (1.0f + __expf(-v));
}
__device__ __forceinline__ unsigned short bf16hi(float f) {
    return (unsigned short)(__float_as_uint(f) >> 16);
}
__device__ __forceinline__ float bf16tof(unsigned short u) {
    return __uint_as_float(((unsigned int)u) << 16);
}
__device__ __forceinline__ f32x16 mfma3(bf16x8 ah, bf16x8 al, bf16x8 bh, bf16x8 bl, f32x16 c) {
    c = __builtin_amdgcn_mfma_f32_32x32x16_bf16(ah, bh, c, 0, 0, 0);
    c = __builtin_amdgcn_mfma_f32_32x32x16_bf16(al, bh, c, 0, 0, 0);
    c = __builtin_amdgcn_mfma_f32_32x32x16_bf16(ah, bl, c, 0, 0, 0);
    return c;
}

// ---------- CSR sort-by-row (rows static across layers) ----------
__global__ void k_cnt(const int* __restrict__ rows, int* __restrict__ cnti, int E) {
    int i = blockIdx.x * 256 + threadIdx.x;
    if (i < E) atomicAdd(&cnti[rows[i]], 1);
}

__global__ void k_scan(const int* __restrict__ cnti, int* __restrict__ base, int N) {
    __shared__ int part[256];
    int t = threadIdx.x;
    int chunk = (N + 255) / 256;
    int lo = t * chunk, hi = lo + chunk < N ? lo + chunk : N;
    int s = 0;
    for (int i = lo; i < hi; ++i) s += cnti[i];
    part[t] = s;
    __syncthreads();
    for (int off = 1; off < 256; off <<= 1) {
        int v = (t >= off) ? part[t - off] : 0;
        __syncthreads();
        part[t] += v;
        __syncthreads();
    }
    int run = (t == 0) ? 0 : part[t - 1];
    for (int i = lo; i < hi; ++i) { base[i] = run; run += cnti[i]; }
}

__global__ void k_scatter(const int* __restrict__ rows, const int* __restrict__ cols,
                          const float* __restrict__ eattr,
                          const int* __restrict__ base, int* __restrict__ fill,
                          int* __restrict__ srow, int* __restrict__ scol,
                          float* __restrict__ sea, int E) {
    int e = blockIdx.x * 256 + threadIdx.x;
    if (e >= E) return;
    int r = rows[e];
    int pos = base[r] + atomicAdd(&fill[r], 1);
    srow[pos] = r;
    scol[pos] = cols[e];
    sea[pos * 2 + 0] = eattr[(size_t)e * 2 + 0];
    sea[pos * 2 + 1] = eattr[(size_t)e * 2 + 1];
}

__global__ void k_embed(const float* __restrict__ hin, const float* __restrict__ w,
                        const float* __restrict__ b, float* __restrict__ hout, int N) {
    int idx = blockIdx.x * 256 + threadIdx.x;
    if (idx >= N * HID) return;
    int n = idx >> 7, j = idx & 127;
    float s = b[j];
    const float* hr = &hin[n * 6];
#pragma unroll
    for (int k = 0; k < 6; ++k) s += hr[k] * w[k * HID + j];
    hout[idx] = s;
}

// pack for mfma_32x32x16 B-layout: off = kc*2048 + n*16 + half*8 + j
// (kc = k>>4, half = (k>>3)&1, j = k&7); split hi/lo arrays
__global__ void k_pack_w(const float* __restrict__ ew1, const float* __restrict__ ew2,
                         const float* __restrict__ cw1,
                         unsigned short* __restrict__ w1h, unsigned short* __restrict__ w1l,
                         unsigned short* __restrict__ w2h, unsigned short* __restrict__ w2l,
                         unsigned short* __restrict__ c1h, unsigned short* __restrict__ c1l) {
    int idx = blockIdx.x * 256 + threadIdx.x;
    if (idx >= 4 * 65536) return;
    int l = idx >> 16, r = idx & 65535;
    const float* src;
    unsigned short *dh, *dl;
    int k, n;
    if (r < 32768) {
        k = r >> 7; n = r & 127;
        src = ew1 + (size_t)l * 33152 + k * 128 + n;
        dh = w1h + (size_t)l * 32768; dl = w1l + (size_t)l * 32768;
    } else if (r < 49152) {
        int rr = r - 32768; k = rr >> 7; n = rr & 127;
        src = ew2 + (size_t)l * 16384 + k * 128 + n;
        dh = w2h + (size_t)l * 16384; dl = w2l + (size_t)l * 16384;
    } else {
        int rr = r - 49152; k = rr >> 7; n = rr & 127;
        src = cw1 + (size_t)l * 16384 + k * 128 + n;
        dh = c1h + (size_t)l * 16384; dl = c1l + (size_t)l * 16384;
    }
    float f = *src;
    unsigned short hi = bf16hi(f);
    float rem = f - bf16tof(hi);
    int off = (k >> 4) * 2048 + n * 16 + ((k >> 3) & 1) * 8 + (k & 7);
    dh[off] = hi; dl[off] = bf16hi(rem);
}

__global__ void k_prep_h(const float* __restrict__ h, unsigned short* __restrict__ hhi,
                         unsigned short* __restrict__ hlo, int N) {
    int idx = blockIdx.x * 256 + threadIdx.x;
    if (idx >= N * HID) return;
    float f = h[idx];
    unsigned short hi = bf16hi(f);
    float rem = f - bf16tof(hi);
    hhi[idx] = hi; hlo[idx] = bf16hi(rem);
}

#define ROWOF(ti, r) ((ti) * 32 + (l5 << 2) + ((r) & 3) + ((((r) >> 2)) << 3))

// Cooperative block tile: 64 edges x 128 N, 4 waves each own a 32-N slice.
// mfma_f32_32x32x16_bf16, split bf16 x3, B streamed from global (L2).
__global__ __launch_bounds__(256, 4) void k_edge_mfma(
    const unsigned short* __restrict__ hhi, const unsigned short* __restrict__ hlo,
    const float* __restrict__ x,
    const int* __restrict__ srow, const int* __restrict__ scol,
    const float* __restrict__ sea,
    const unsigned short* __restrict__ w1h, const unsigned short* __restrict__ w1l,
    const float* __restrict__ ew1_tail, const float* __restrict__ eb1,
    const unsigned short* __restrict__ w2h, const unsigned short* __restrict__ w2l,
    const float* __restrict__ eb2,
    const float* __restrict__ aw, const float* __restrict__ ab,
    const unsigned short* __restrict__ c1h, const unsigned short* __restrict__ c1l,
    const float* __restrict__ cb1, const float* __restrict__ cw2,
    float* __restrict__ aggh, float* __restrict__ aggx, int E)
{
    __shared__ __align__(16) unsigned short tHi[64][136];
    __shared__ __align__(16) unsigned short tLo[64][136];
    __shared__ float sCD[64][4];
    __shared__ float sEA[64][2];
    __shared__ int sRow[64], sCol[64];
    __shared__ int sFlag[64];
    __shared__ float attp[4][64];
    __shared__ float attL[64];
    __shared__ float wcp[4][64];

    const int t = threadIdx.x;
    const int wv = t >> 6, lane = t & 63;
    const int l5 = lane >> 5, ll = lane & 31;
    const int e0 = blockIdx.x * 64;

    if (t < 64) {
        int eg = e0 + t;
        int ec = eg < E ? eg : E - 1;
        int r = srow[ec], c = scol[ec];
        sRow[t] = r; sCol[t] = c;
        float dx = x[r * 3 + 0] - x[c * 3 + 0];
        float dy = x[r * 3 + 1] - x[c * 3 + 1];
        float dz = x[r * 3 + 2] - x[c * 3 + 2];
        sCD[t][0] = dx; sCD[t][1] = dy; sCD[t][2] = dz;
        sCD[t][3] = dx * dx + dy * dy + dz * dz;
        sEA[t][0] = sea[(size_t)ec * 2 + 0];
        sEA[t][1] = sea[(size_t)ec * 2 + 1];
        sFlag[t] = (t == 0) || (sRow[t] != sRow[t - 1]);
    }
    __syncthreads();

    const int nl = (wv << 5) + ll;           // this lane's output column 0..127
    const float w6 = ew1_tail[nl], w7 = ew1_tail[128 + nl], w8 = ew1_tail[256 + nl];
    const float b1v = eb1[nl], b2v = eb2[nl], awv = aw[nl];
    const float cb1v = cb1[nl], cw2v = cw2[nl];
    const float ab0 = ab[0];

    int rN0 = sRow[ll], rN1 = sRow[ll + 32];
    int cN0 = sCol[ll], cN1 = sCol[ll + 32];
    unsigned long long runmask = __ballot(sFlag[lane] != 0);

    // ---- GEMM1: t1 = e_in[0:256] @ ew1 ----
    f32x16 acc[2];
#pragma unroll
    for (int i = 0; i < 2; ++i)
#pragma unroll
        for (int j = 0; j < 16; ++j) acc[i][j] = 0.f;
#pragma unroll 2
    for (int kc = 0; kc < 16; ++kc) {
        int n0 = (kc < 8) ? rN0 : cN0;
        int n1 = (kc < 8) ? rN1 : cN1;
        int ko = ((kc & 7) << 4) + (l5 << 3);
        bf16x8 a0h = *(const bf16x8*)(hhi + (size_t)n0 * HID + ko);
        bf16x8 a0l = *(const bf16x8*)(hlo + (size_t)n0 * HID + ko);
        bf16x8 a1h = *(const bf16x8*)(hhi + (size_t)n1 * HID + ko);
        bf16x8 a1l = *(const bf16x8*)(hlo + (size_t)n1 * HID + ko);
        int boff = kc * 2048 + nl * 16 + (l5 << 3);
        bf16x8 bh = *(const bf16x8*)(w1h + boff);
        bf16x8 bl = *(const bf16x8*)(w1l + boff);
        acc[0] = mfma3(a0h, a0l, bh, bl, acc[0]);
        acc[1] = mfma3(a1h, a1l, bh, bl, acc[1]);
    }
    // epilogue1: + tail(radial, eattr) + bias, silu -> act LDS (hi/lo)
#pragma unroll
    for (int ti = 0; ti < 2; ++ti)
#pragma unroll
        for (int r = 0; r < 16; ++r) {
            int row = ROWOF(ti, r);
            float v = acc[ti][r] + sCD[row][3] * w6 + sEA[row][0] * w7 + sEA[row][1] * w8 + b1v;
            v = silu_f(v);
            unsigned short hi = bf16hi(v);
            tHi[row][nl] = hi;
            tLo[row][nl] = bf16hi(v - bf16tof(hi));
        }
    __syncthreads();

    // ---- GEMM2: t2 = t1 @ ew2 ----
    f32x16 acc2[2];
#pragma unroll
    for (int i = 0; i < 2; ++i)
#pragma unroll
        for (int j = 0; j < 16; ++j) acc2[i][j] = 0.f;
#pragma unroll 2
    for (int kc = 0; kc < 8; ++kc) {
        int ko = (kc << 4) + (l5 << 3);
        bf16x8 a0h = *(const bf16x8*)&tHi[ll][ko];
        bf16x8 a0l = *(const bf16x8*)&tLo[ll][ko];
        bf16x8 a1h = *(const bf16x8*)&tHi[ll + 32][ko];
        bf16x8 a1l = *(const bf16x8*)&tLo[ll + 32][ko];
        int boff = kc * 2048 + nl * 16 + (l5 << 3);
        bf16x8 bh = *(const bf16x8*)(w2h + boff);
        bf16x8 bl = *(const bf16x8*)(w2l + boff);
        acc2[0] = mfma3(a0h, a0l, bh, bl, acc2[0]);
        acc2[1] = mfma3(a1h, a1l, bh, bl, acc2[1]);
    }
    // epilogue2: silu, per-row attention dot partials (shfl over 32-col slice)
#pragma unroll
    for (int ti = 0; ti < 2; ++ti)
#pragma unroll
        for (int r = 0; r < 16; ++r) {
            float v = silu_f(acc2[ti][r] + b2v);
            acc2[ti][r] = v;
            float p = v * awv;
            p += __shfl_xor(p, 1);
            p += __shfl_xor(p, 2);
            p += __shfl_xor(p, 4);
            p += __shfl_xor(p, 8);
            p += __shfl_xor(p, 16);
            if (ll == 0) attp[wv][ROWOF(ti, r)] = p;
        }
    __syncthreads();
    if (t < 64) attL[t] = sigmoid_f(attp[0][t] + attp[1][t] + attp[2][t] + attp[3][t] + ab0);
    __syncthreads();
    // gate -> m (regs + act LDS overwrite)
#pragma unroll
    for (int ti = 0; ti < 2; ++ti)
#pragma unroll
        for (int r = 0; r < 16; ++r) {
            int row = ROWOF(ti, r);
            float v = acc2[ti][r] * attL[row];
            acc2[ti][r] = v;
            unsigned short hi = bf16hi(v);
            tHi[row][nl] = hi;
            tLo[row][nl] = bf16hi(v - bf16tof(hi));
        }
    __syncthreads();

    // ---- GEMM3: u = silu(m @ cw1 + cb1); wc = u @ cw2 ----
    f32x16 acc3[2];
#pragma unroll
    for (int i = 0; i < 2; ++i)
#pragma unroll
        for (int j = 0; j < 16; ++j) acc3[i][j] = 0.f;
#pragma unroll 2
    for (int kc = 0; kc < 8; ++kc) {
        int ko = (kc << 4) + (l5 << 3);
        bf16x8 a0h = *(const bf16x8*)&tHi[ll][ko];
        bf16x8 a0l = *(const bf16x8*)&tLo[ll][ko];
        bf16x8 a1h = *(const bf16x8*)&tHi[ll + 32][ko];
        bf16x8 a1l = *(const bf16x8*)&tLo[ll + 32][ko];
        int boff = kc * 2048 + nl * 16 + (l5 << 3);
        bf16x8 bh = *(const bf16x8*)(c1h + boff);
        bf16x8 bl = *(const bf16x8*)(c1l + boff);
        acc3[0] = mfma3(a0h, a0l, bh, bl, acc3[0]);
        acc3[1] = mfma3(a1h, a1l, bh, bl, acc3[1]);
    }

    // ---- agg_h: run-segmented reduction over 64 sorted edges (m in acc2) ----
    {
        int i = 0;
        while (i < 64) {
            unsigned long long rest = (i < 63) ? (runmask >> (i + 1)) : 0ULL;
            int j = rest ? (i + 1 + __ffsll((unsigned long long)rest) - 1) : 64;
            int node = sRow[i];
            float s = 0.f;
#pragma unroll
            for (int ti = 0; ti < 2; ++ti)
#pragma unroll
                for (int r = 0; r < 16; ++r) {
                    int row = ROWOF(ti, r);
                    bool ok = (row >= i) && (row < j) && (e0 + row < E);
                    s += ok ? acc2[ti][r] : 0.f;
                }
            s += __shfl_xor(s, 32);
            if (lane < 32) atomicAdd(&aggh[(size_t)node * HID + nl], s);
            i = j;
        }
    }

    // epilogue3: per-row wc partials
#pragma unroll
    for (int ti = 0; ti < 2; ++ti)
#pragma unroll
        for (int r = 0; r < 16; ++r) {
            float u = silu_f(acc3[ti][r] + cb1v);
            float p = u * cw2v;
            p += __shfl_xor(p, 1);
            p += __shfl_xor(p, 2);
            p += __shfl_xor(p, 4);
            p += __shfl_xor(p, 8);
            p += __shfl_xor(p, 16);
            if (ll == 0) wcp[wv][ROWOF(ti, r)] = p;
        }
    __syncthreads();
    if (t < 64 && e0 + t < E) {
        float wc = wcp[0][t] + wcp[1][t] + wcp[2][t] + wcp[3][t];
        int node = sRow[t];
#pragma unroll
        for (int d = 0; d < 3; ++d)
            atomicAdd(&aggx[node * 3 + d], sCD[t][d] * wc);
    }
}

// 64 nodes per block, 256 threads (fp32)
__global__ __launch_bounds__(256, 2) void k_node(
    float* __restrict__ h, const float* __restrict__ aggh,
    const float* __restrict__ aggx, const int* __restrict__ cnti,
    float* __restrict__ x, float* __restrict__ vel,
    const float* __restrict__ vw1, const float* __restrict__ vb1,
    const float* __restrict__ vw2, const float* __restrict__ vb2,
    const float* __restrict__ nw1, const float* __restrict__ nb1,
    const float* __restrict__ nw2, const float* __restrict__ nb2,
    int N)
{
    __shared__ __align__(16) float BH[64][132];
    __shared__ __align__(16) float BG[64][132];
    const int t = threadIdx.x;
    const int tx = t & 15, ty = t >> 4;
    const int n0 = blockIdx.x * 64;

    for (int idx = t; idx < 64 * 32; idx += 256) {
        int r = idx >> 5, c4 = idx & 31;
        int n = n0 + r;
        float4 v0 = make_float4(0.f, 0.f, 0.f, 0.f), v1 = v0;
        if (n < N) {
            v0 = *(const float4*)&h[(size_t)n * HID + c4 * 4];
            v1 = *(const float4*)&aggh[(size_t)n * HID + c4 * 4];
        }
        *(float4*)&BH[r][c4 * 4] = v0;
        *(float4*)&BG[r][c4 * 4] = v1;
    }
    __syncthreads();

    {
        float acc[4][8];
#pragma unroll
        for (int i = 0; i < 4; ++i)
#pragma unroll
            for (int j = 0; j < 8; ++j) acc[i][j] = 0.f;
        const float* wp = &vw1[tx * 8];
#pragma unroll 4
        for (int k = 0; k < HID; ++k) {
            float4 w0 = *(const float4*)&wp[k * HID];
            float4 w1v = *(const float4*)&wp[k * HID + 4];
            float wvv[8] = {w0.x, w0.y, w0.z, w0.w, w1v.x, w1v.y, w1v.z, w1v.w};
            float av[4];
#pragma unroll
            for (int i = 0; i < 4; ++i) av[i] = BH[ty * 4 + i][k];
#pragma unroll
            for (int i = 0; i < 4; ++i)
#pragma unroll
                for (int j = 0; j < 8; ++j) acc[i][j] += av[i] * wvv[j];
        }
        float bb[8], w2v[8];
#pragma unroll
        for (int j = 0; j < 8; ++j) { bb[j] = vb1[tx * 8 + j]; w2v[j] = vw2[tx * 8 + j]; }
        float vb20 = vb2[0];
#pragma unroll
        for (int i = 0; i < 4; ++i) {
            float p = 0.f;
#pragma unroll
            for (int j = 0; j < 8; ++j) p += silu_f(acc[i][j] + bb[j]) * w2v[j];
            p += __shfl_xor(p, 1);
            p += __shfl_xor(p, 2);
            p += __shfl_xor(p, 4);
            p += __shfl_xor(p, 8);
            float vs = p + vb20;
            if (tx == 0) {
                int n = n0 + ty * 4 + i;
                if (n < N) {
                    float cc = fmaxf((float)cnti[n], 1.0f);
#pragma unroll
                    for (int d = 0; d < 3; ++d) {
                        float vn = vs * vel[n * 3 + d];
                        float xn = x[n * 3 + d] + aggx[n * 3 + d] / cc + vn;
                        vel[n * 3 + d] = vn;
                        x[n * 3 + d] = xn;
                    }
                }
            }
        }
    }

    float acc2[4][8];
#pragma unroll
    for (int i = 0; i < 4; ++i)
#pragma unroll
        for (int j = 0; j < 8; ++j) acc2[i][j] = 0.f;
    {
        const float* wp = &nw1[tx * 8];
#pragma unroll 4
        for (int k = 0; k < HID; ++k) {
            float4 w0 = *(const float4*)&wp[k * HID];
            float4 w1v = *(const float4*)&wp[k * HID + 4];
            float wvv[8] = {w0.x, w0.y, w0.z, w0.w, w1v.x, w1v.y, w1v.z, w1v.w};
            float av[4];
#pragma unroll
            for (int i = 0; i < 4; ++i) av[i] = BH[ty * 4 + i][k];
#pragma unroll
            for (int i = 0; i < 4; ++i)
#pragma unroll
                for (int j = 0; j < 8; ++j) acc2[i][j] += av[i] * wvv[j];
        }
        const float* wp2 = &nw1[128 * HID + tx * 8];
#pragma unroll 4
        for (int k = 0; k < HID; ++k) {
            float4 w0 = *(const float4*)&wp2[k * HID];
            float4 w1v = *(const float4*)&wp2[k * HID + 4];
            float wvv[8] = {w0.x, w0.y, w0.z, w0.w, w1v.x, w1v.y, w1v.z, w1v.w};
            float av[4];
#pragma unroll
            for (int i = 0; i < 4; ++i) av[i] = BG[ty * 4 + i][k];
#pragma unroll
            for (int i = 0; i < 4; ++i)
#pragma unroll
                for (int j = 0; j < 8; ++j) acc2[i][j] += av[i] * wvv[j];
        }
    }
    __syncthreads();
    {
        float bb[8];
#pragma unroll
        for (int j = 0; j < 8; ++j) bb[j] = nb1[tx * 8 + j];
#pragma unroll
        for (int i = 0; i < 4; ++i)
#pragma unroll
            for (int j = 0; j < 8; ++j)
                BH[ty * 4 + i][tx * 8 + j] = silu_f(acc2[i][j] + bb[j]);
    }
    __syncthreads();
    float acc3[4][8];
#pragma unroll
    for (int i = 0; i < 4; ++i)
#pragma unroll
        for (int j = 0; j < 8; ++j) acc3[i][j] = 0.f;
    {
        const float* wp = &nw2[tx * 8];
#pragma unroll 4
        for (int k = 0; k < HID; ++k) {
            float4 w0 = *(const float4*)&wp[k * HID];
            float4 w1v = *(const float4*)&wp[k * HID + 4];
            float wvv[8] = {w0.x, w0.y, w0.z, w0.w, w1v.x, w1v.y, w1v.z, w1v.w};
            float av[4];
#pragma unroll
            for (int i = 0; i < 4; ++i) av[i] = BH[ty * 4 + i][k];
#pragma unroll
            for (int i = 0; i < 4; ++i)
#pragma unroll
                for (int j = 0; j < 8; ++j) acc3[i][j] += av[i] * wvv[j];
        }
    }
    {
        float bb[8];
#pragma unroll
        for (int j = 0; j < 8; ++j) bb[j] = nb2[tx * 8 + j];
#pragma unroll
        for (int i = 0; i < 4; ++i) {
            int n = n0 + ty * 4 + i;
            if (n < N) {
#pragma unroll
                for (int j = 0; j < 8; ++j)
                    h[(size_t)n * HID + tx * 8 + j] = acc3[i][j] + bb[j];
            }
        }
    }
}

__global__ void k_proj(const float* __restrict__ h, const float* __restrict__ pw,
                       const float* __restrict__ pb, float* __restrict__ out, int N) {
    int idx = blockIdx.x * 256 + threadIdx.x;
    if (idx >= N * 3) return;
    int n = idx / 3, p = idx % 3;
    float s = pb[p];
    const float* hr = &h[(size_t)n * HID];
#pragma unroll 8
    for (int k = 0; k < HID; ++k) s += hr[k] * pw[k * 3 + p];
    out[idx] = s;
}

extern "C" void kernel_launch(void* const* d_in, const int* in_sizes, int n_in,
                              void* d_out, int out_size, void* d_ws, size_t ws_size,
                              hipStream_t stream)
{
    const float* h_in  = (const float*)d_in[0];
    const float* x_in  = (const float*)d_in[1];
    const float* v_in  = (const float*)d_in[2];
    const float* eattr = (const float*)d_in[3];
    const int*   edges = (const int*)d_in[4];
    const float* emb_w = (const float*)d_in[5];
    const float* emb_b = (const float*)d_in[6];
    const float* ew1   = (const float*)d_in[7];
    const float* eb1   = (const float*)d_in[8];
    const float* ew2   = (const float*)d_in[9];
    const float* eb2   = (const float*)d_in[10];
    const float* aw    = (const float*)d_in[11];
    const float* ab    = (const float*)d_in[12];
    const float* nw1   = (const float*)d_in[13];
    const float* nb1   = (const float*)d_in[14];
    const float* nw2   = (const float*)d_in[15];
    const float* nb2   = (const float*)d_in[16];
    const float* cw1   = (const float*)d_in[17];
    const float* cb1   = (const float*)d_in[18];
    const float* cw2   = (const float*)d_in[19];
    const float* vw1   = (const float*)d_in[20];
    const float* vb1   = (const float*)d_in[21];
    const float* vw2   = (const float*)d_in[22];
    const float* vb2   = (const float*)d_in[23];
    const float* pw    = (const float*)d_in[24];
    const float* pb    = (const float*)d_in[25];

    const int N = in_sizes[0] / 6;
    const int E = in_sizes[4] / 2;
    const int* rows = edges;
    const int* cols = edges + E;

    float* ws   = (float*)d_ws;
    float* hbuf = ws;  ws += (size_t)N * HID;
    float* aggh = ws;  ws += (size_t)N * HID;
    float* aggx = ws;  ws += (size_t)N * 3;
    float* xb   = ws;  ws += (size_t)N * 3;
    float* vb   = ws;  ws += (size_t)N * 3;
    float* sea  = ws;  ws += (size_t)E * 2;
    int* wi = (int*)ws;
    int* cnti = wi;  wi += N;
    int* basei = wi; wi += N;
    int* fill = wi;  wi += N;
    int* srow = wi;  wi += E;
    int* scol = wi;  wi += E;
    unsigned short* us = (unsigned short*)wi;
    unsigned short* hhi = us;  us += (size_t)N * HID;
    unsigned short* hlo = us;  us += (size_t)N * HID;
    unsigned short* w1h = us;  us += 4 * 32768;
    unsigned short* w1l = us;  us += 4 * 32768;
    unsigned short* w2h = us;  us += 4 * 16384;
    unsigned short* w2l = us;  us += 4 * 16384;
    unsigned short* c1h = us;  us += 4 * 16384;
    unsigned short* c1l = us;  us += 4 * 16384;
    float* outp = (float*)d_out;

    hipMemcpyAsync(xb, x_in, (size_t)N * 3 * sizeof(float), hipMemcpyDeviceToDevice, stream);
    hipMemcpyAsync(vb, v_in, (size_t)N * 3 * sizeof(float), hipMemcpyDeviceToDevice, stream);
    hipMemsetAsync(cnti, 0, N * sizeof(int), stream);
    hipMemsetAsync(fill, 0, N * sizeof(int), stream);
    k_cnt<<<(E + 255) / 256, 256, 0, stream>>>(rows, cnti, E);
    k_scan<<<1, 256, 0, stream>>>(cnti, basei, N);
    k_scatter<<<(E + 255) / 256, 256, 0, stream>>>(rows, cols, eattr, basei, fill,
                                                   srow, scol, sea, E);
    k_pack_w<<<(4 * 65536 + 255) / 256, 256, 0, stream>>>(ew1, ew2, cw1,
                                                          w1h, w1l, w2h, w2l, c1h, c1l);
    k_embed<<<(N * HID + 255) / 256, 256, 0, stream>>>(h_in, emb_w, emb_b, hbuf, N);

    for (int l = 0; l < 4; ++l) {
        k_prep_h<<<(N * HID + 255) / 256, 256, 0, stream>>>(hbuf, hhi, hlo, N);
        hipMemsetAsync(aggh, 0, (size_t)N * HID * sizeof(float), stream);
        hipMemsetAsync(aggx, 0, (size_t)N * 3 * sizeof(float), stream);
        k_edge_mfma<<<(E + 63) / 64, 256, 0, stream>>>(
            hhi, hlo, xb, srow, scol, sea,
            w1h + (size_t)l * 32768, w1l + (size_t)l * 32768,
            ew1 + (size_t)l * 33152 + 256 * HID, eb1 + l * HID,
            w2h + (size_t)l * 16384, w2l + (size_t)l * 16384, eb2 + l * HID,
            aw + l * HID, ab + l,
            c1h + (size_t)l * 16384, c1l + (size_t)l * 16384,
            cb1 + l * HID, cw2 + l * HID,
            aggh, aggx, E);
        k_node<<<(N + 63) / 64, 256, 0, stream>>>(
            hbuf, aggh, aggx, cnti, xb, vb,
            vw1 + (size_t)l * HID * HID, vb1 + l * HID, vw2 + l * HID, vb2 + l,
            nw1 + (size_t)l * 2 * HID * HID, nb1 + l * HID,
            nw2 + (size_t)l * HID * HID, nb2 + l * HID, N);
    }
    k_proj<<<(N * 3 + 255) / 256, 256, 0, stream>>>(hbuf, pw, pb, outp, N);
    hipMemcpyAsync(outp + (size_t)N * 3, xb, (size_t)N * 3 * sizeof(float), hipMemcpyDeviceToDevice, stream);
    hipMemcpyAsync(outp + (size_t)N * 6, vb, (size_t)N * 3 * sizeof(float), hipMemcpyDeviceToDevice, stream);
}